// Round 5
// baseline (878.258 us; speedup 1.0000x reference)
//
#include <hip/hip_runtime.h>

// ---------------------------------------------------------------------------
// UAActor MC-dropout ADF MLP, MI355X/gfx950.
// B=32768 S=512 H1=400 H2=300 A=8 N=3.  Inputs f32 (runtime-detected, bf16
// fallback).  Internal GEMM operands bf16.
//
// R5: single fused kernel (k_fused), BM=16 rows/block, 2048 blocks, 256 thr.
// LDS = one 26 KB time-multiplexed region (xS -> oS/vS -> pmS/pvS -> m2s/v2s)
// + tiny exch. om/ov in 32 VGPRs (packet layout). mask2 reg-prefetch.
// No omov global round-trip; k_l1 eliminated.
// ---------------------------------------------------------------------------

typedef unsigned short u16;
typedef unsigned int u32;
typedef float f32x4 __attribute__((ext_vector_type(4)));
typedef __bf16 bf16x8 __attribute__((ext_vector_type(8)));
typedef u32 u32x4 __attribute__((ext_vector_type(4)));

union U4 { u32x4 u; bf16x8 v; u16 s[8]; };

#define MFMA16(a, b, c) __builtin_amdgcn_mfma_f32_16x16x32_bf16(a, b, c, 0, 0, 0)

#define B_N 32768
#define S_N 512
#define H1_N 400
#define H2_N 300
#define A_N 8

__device__ __forceinline__ float bf2f(u16 h) {
    union { float f; u32 u; } c; c.u = ((u32)h) << 16; return c.f;
}
__device__ __forceinline__ u16 f2bfbits(float f) {  // RNE
    u32 u = __float_as_uint(f);
    u32 r = 0x7FFFu + ((u >> 16) & 1u);
    return (u16)((u + r) >> 16);
}
__device__ __forceinline__ u32 encf(float f) {
    u32 u = __float_as_uint(f);
    return (u & 0x80000000u) ? ~u : (u | 0x80000000u);
}
__device__ __forceinline__ float decf(u32 e) {
    u32 u = (e >> 31) ? (e & 0x7FFFFFFFu) : ~e;
    return __uint_as_float(u);
}

// ADF ReLU moment matching; shares one exp between erf (A&S 7.1.26) and pdf.
__device__ __forceinline__ void adf_relu(float m, float v, float& om, float& ov) {
    v = fmaxf(v, 1e-12f);
    float rstd = rsqrtf(v);
    float stdv = v * rstd;
    float r = m * rstd;
    float e = __expf(-0.5f * r * r);
    float ar = fabsf(r) * 0.70710678118654752f;
    float t = __builtin_amdgcn_rcpf(fmaf(0.3275911f, ar, 1.0f));
    float poly = t * (0.254829592f + t * (-0.284496736f + t * (1.421413741f +
                  t * (-1.453152027f + t * 1.061405429f))));
    float erfa = 1.0f - poly * e;
    float erfv = (r < 0.0f) ? -erfa : erfa;
    float cdf = 0.5f * (1.0f + erfv);
    float pdf = 0.3989422804014327f * e;
    om = fmaf(m, cdf, stdv * pdf);
    ov = fmaf(m * m + v, cdf, m * stdv * pdf) - om * om;
    ov = fmaxf(ov, 0.0f);
}

// ---------------- workspace layout (bytes) ----------------
#define WS_CTL    0u          // u32[16]: [0]=is_bf16, [1]=encmin, [2]=encmax
#define WS_B1F    64u         // 400 f32
#define WS_B2F    1664u       // 300 f32
#define WS_B3F    2880u       // 8 f32
#define WS_RS1    2944u       // 400 f32
#define WS_VC1    4544u       // 400 f32
#define WS_W3M    6144u       // 16*320 bf16 (zero padded)
#define WS_W3V    16384u      // 16*320 bf16 (squares)
#define WS_W2SQ   26624u      // 300*400 bf16
#define WS_W2B    266624u     // 300*400 bf16 (f32 mode: converted W2)
#define WS_W1B    506624u     // 400*512 bf16 (f32 mode: converted W1)

// ---------------- dtype detect + ctl init ----------------
__global__ void k_detect(const u32* __restrict__ xw, u32* __restrict__ ctl) {
    if (threadIdx.x == 0) {
        int votes = 0;
        for (int i = 0; i < 64; ++i) {
            u32 u = xw[i * 997];
            u32 e = (u >> 7) & 0xFFu;
            votes += (e >= 100u && e <= 145u) ? 1 : 0;
        }
        ctl[0] = (votes >= 40) ? 1u : 0u;
        ctl[1] = 0xFFFFFFFFu;   // encoded min slot
        ctl[2] = 0u;            // encoded max slot
    }
}

// ---------------- weights prep (both modes) ----------------
__global__ void k_weights(const void* __restrict__ w1r, const void* __restrict__ w2r,
                          const void* __restrict__ w3r, const void* __restrict__ b1r,
                          const void* __restrict__ b2r, const void* __restrict__ b3r,
                          const u32* __restrict__ ctl,
                          u16* __restrict__ w1b, u16* __restrict__ w2b,
                          u16* __restrict__ w2sq, u16* __restrict__ w3m,
                          u16* __restrict__ w3v, float* __restrict__ b1f,
                          float* __restrict__ b2f, float* __restrict__ b3f) {
    const bool bf = ctl[0] != 0u;
    const int t = blockIdx.x * 256 + threadIdx.x;

    if (t < (H2_N * H1_N / 8)) {  // W2 -> w2sq (+ W2B in f32 mode)
        float f[8];
        if (bf) {
            U4 d; d.u = *(const u32x4*)((const u16*)w2r + (size_t)t * 8);
            #pragma unroll
            for (int j = 0; j < 8; ++j) f[j] = bf2f(d.s[j]);
        } else {
            f32x4 a = *((const f32x4*)w2r + (size_t)t * 2);
            f32x4 b = *((const f32x4*)w2r + (size_t)t * 2 + 1);
            #pragma unroll
            for (int j = 0; j < 4; ++j) { f[j] = a[j]; f[4 + j] = b[j]; }
        }
        u16 sq[8], cv[8];
        #pragma unroll
        for (int j = 0; j < 8; ++j) { sq[j] = f2bfbits(f[j] * f[j]); cv[j] = f2bfbits(f[j]); }
        *(u32x4*)(w2sq + (size_t)t * 8) = *(u32x4*)sq;
        if (!bf) *(u32x4*)(w2b + (size_t)t * 8) = *(u32x4*)cv;
    }
    if (!bf && t < (H1_N * S_N / 8)) {  // W1 convert (f32 mode only)
        f32x4 a = *((const f32x4*)w1r + (size_t)t * 2);
        f32x4 b = *((const f32x4*)w1r + (size_t)t * 2 + 1);
        u16 cv[8];
        #pragma unroll
        for (int j = 0; j < 4; ++j) { cv[j] = f2bfbits(a[j]); cv[4 + j] = f2bfbits(b[j]); }
        *(u32x4*)(w1b + (size_t)t * 8) = *(u32x4*)cv;
    }
    if (t < 16 * 320) {  // padded W3 tables
        int col = t / 320, k = t - col * 320;
        float f = 0.0f;
        if (col < A_N && k < H2_N)
            f = bf ? bf2f(((const u16*)w3r)[col * H2_N + k]) : ((const float*)w3r)[col * H2_N + k];
        w3m[t] = f2bfbits(f);
        w3v[t] = f2bfbits(f * f);
    }
    if (t < H1_N) b1f[t] = bf ? bf2f(((const u16*)b1r)[t]) : ((const float*)b1r)[t];
    if (t < H2_N) b2f[t] = bf ? bf2f(((const u16*)b2r)[t]) : ((const float*)b2r)[t];
    if (t < A_N)  b3f[t] = bf ? bf2f(((const u16*)b3r)[t]) : ((const float*)b3r)[t];
}

// ---------------- global min/max of x ----------------
__global__ void k_minmax(const void* __restrict__ xr, u32* __restrict__ ctl) {
    const int tid = threadIdx.x, lane = tid & 63, wv = tid >> 6;
    const bool bf = ctl[0] != 0u;
    float mn = 3.0e38f, mx = -3.0e38f;
    const int idx = blockIdx.x * 256 + tid;
    if (bf) {
        const u16* xg = (const u16*)xr;
        for (int i = idx; i < (B_N * S_N / 8); i += 2048 * 256) {
            U4 d; d.u = *(const u32x4*)(xg + (size_t)i * 8);
            #pragma unroll
            for (int j = 0; j < 8; ++j) {
                float f = bf2f(d.s[j]);
                mn = fminf(mn, f); mx = fmaxf(mx, f);
            }
        }
    } else {
        const f32x4* xf = (const f32x4*)xr;
        for (int i = idx; i < (B_N * S_N / 4); i += 2048 * 256) {
            f32x4 d = xf[i];
            #pragma unroll
            for (int j = 0; j < 4; ++j) {
                mn = fminf(mn, d[j]); mx = fmaxf(mx, d[j]);
            }
        }
    }
    #pragma unroll
    for (int off = 32; off >= 1; off >>= 1) {
        mn = fminf(mn, __shfl_xor(mn, off));
        mx = fmaxf(mx, __shfl_xor(mx, off));
    }
    __shared__ float rmn[4], rmx[4];
    if (lane == 0) { rmn[wv] = mn; rmx[wv] = mx; }
    __syncthreads();
    if (tid == 0) {
        for (int w = 1; w < 4; ++w) { mn = fminf(mn, rmn[w]); mx = fmaxf(mx, rmx[w]); }
        atomicMin(&ctl[1], encf(mn));
        atomicMax(&ctl[2], encf(mx));
    }
}

// ---------------- W1 row sums + variance constant ----------------
__global__ void k_prep(const void* __restrict__ w1r, const u32* __restrict__ ctl,
                       float* __restrict__ rs1, float* __restrict__ vc1) {
    const bool bf = ctl[0] != 0u;
    const int h = blockIdx.x, lane = threadIdx.x;
    float f[8];
    if (bf) {
        U4 d; d.u = *(const u32x4*)((const u16*)w1r + (size_t)h * S_N + lane * 8);
        #pragma unroll
        for (int j = 0; j < 8; ++j) f[j] = bf2f(d.s[j]);
    } else {
        f32x4 a = *((const f32x4*)w1r + (size_t)h * 128 + lane * 2);
        f32x4 b = *((const f32x4*)w1r + (size_t)h * 128 + lane * 2 + 1);
        #pragma unroll
        for (int j = 0; j < 4; ++j) { f[j] = a[j]; f[4 + j] = b[j]; }
    }
    float s1 = 0.f, s2 = 0.f;
    #pragma unroll
    for (int j = 0; j < 8; ++j) { s1 += f[j]; s2 += f[j] * f[j]; }
    #pragma unroll
    for (int off = 32; off >= 1; off >>= 1) {
        s1 += __shfl_xor(s1, off);
        s2 += __shfl_xor(s2, off);
    }
    if (lane == 0) { rs1[h] = s1; vc1[h] = 2.0001f * s2; }
}

// ---------------- fully fused MLP: 16 rows/block, 2048 blocks ----------------
// LDS region A (26112 B) time-multiplexed:
//   phase0: xS[16][520] bf16         (x staged, f32->bf16)
//   phase1e: oS[16][408] / vS[16][408]  (layer1 om/ov)
//   per n:  pmS/pvS[16][408]  ->  m2s/v2s[16][328]
// om/ov persist in 32 VGPRs (packet layout). mask2 reg-prefetched (20 VGPR).
__global__ __launch_bounds__(256, 4)
void k_fused(const void* __restrict__ xr, const u16* __restrict__ w1bf,
             const u16* __restrict__ w1cv, const u16* __restrict__ w2bf,
             const u16* __restrict__ w2cv, const u16* __restrict__ w2sqg,
             const void* __restrict__ m1r, const void* __restrict__ m2r,
             const float* __restrict__ b1f, const float* __restrict__ b2f,
             const float* __restrict__ b3f, const float* __restrict__ rs1,
             const float* __restrict__ vc1, const u16* __restrict__ w3mg,
             const u16* __restrict__ w3vg, const u32* __restrict__ ctl,
             void* __restrict__ outr) {
    __shared__ __align__(16) unsigned char smem[26624];
    u16* xS  = (u16*)smem;                 // [16][520]
    u16* oS  = (u16*)smem;                 // [16][408]
    u16* vS  = (u16*)(smem + 13056);       // [16][408]
    u16* pmS = (u16*)smem;                 // [16][408]
    u16* pvS = (u16*)(smem + 13056);       // [16][408]
    u16* m2s = (u16*)smem;                 // [16][328]
    u16* v2s = (u16*)(smem + 13056);       // [16][328]
    float* exch = (float*)(smem + 26112);  // [16][8]

    const int tid = threadIdx.x;
    const int wv = tid >> 6, lane = tid & 63;
    const int cq = wv;
    const int lrow = lane & 15, lgrp = lane >> 4;
    const int m0 = blockIdx.x * 16;
    const bool bf = ctl[0] != 0u;
    const u16* w1 = bf ? w1bf : w1cv;
    const u16* w2 = bf ? w2bf : w2cv;
    const float xmin = decf(ctl[1]), xmax = decf(ctl[2]);
    const float inv = 1.0f / (xmax - xmin);
    const float csh = 0.1f - xmin * inv;
    const f32x4 fz = {0.f, 0.f, 0.f, 0.f};

    // ---- phase 0: stage x (16 rows x 512) as bf16 into xS ----
    {
        const int row = tid >> 4, ks0 = (tid & 15) * 32;
        const size_t gbase = (size_t)(m0 + row) * S_N + ks0;
        if (bf) {
            const u16* xg = (const u16*)xr;
            #pragma unroll
            for (int i = 0; i < 4; ++i)
                *(u32x4*)(xS + row * 520 + ks0 + i * 8) =
                    *(const u32x4*)(xg + gbase + i * 8);
        } else {
            const f32x4* xf = (const f32x4*)xr;
            const size_t q = gbase >> 2;
            #pragma unroll
            for (int i = 0; i < 4; ++i) {
                f32x4 a = xf[q + i * 2], b = xf[q + i * 2 + 1];
                u16 cv[8];
                #pragma unroll
                for (int j = 0; j < 4; ++j) { cv[j] = f2bfbits(a[j]); cv[4 + j] = f2bfbits(b[j]); }
                *(u32x4*)(xS + row * 520 + ks0 + i * 8) = *(u32x4*)cv;
            }
        }
    }
    __syncthreads();

    // ---- phase 1: layer1 GEMM (tiles t = cq + 4*j, t < 25) ----
    f32x4 a1[7];
    #pragma unroll
    for (int j = 0; j < 7; ++j) a1[j] = fz;
    #pragma unroll 1
    for (int ks = 0; ks < 16; ++ks) {
        const bf16x8 amf = *(const bf16x8*)(xS + lrow * 520 + ks * 32 + lgrp * 8);
        const int k = ks * 32 + lgrp * 8;
        #pragma unroll
        for (int j = 0; j < 7; ++j) {
            const int t = cq + 4 * j;
            if (t < 25) {
                const int col = t * 16 + lrow;
                U4 b; b.u = *(const u32x4*)(w1 + (size_t)col * S_N + k);
                a1[j] = MFMA16(amf, b.v, a1[j]);
            }
        }
    }
    __syncthreads();  // xS reads done; oS/vS writes next (aliased)

    // ---- phase 1e: ADF ReLU -> oS/vS ----
    #pragma unroll
    for (int j = 0; j < 7; ++j) {
        const int t = cq + 4 * j;
        if (t < 25) {
            const int col = t * 16 + lrow;
            const float c1 = csh * rs1[col] + b1f[col];
            const float vv1 = vc1[col];
            #pragma unroll
            for (int r = 0; r < 4; ++r) {
                const int row = lgrp * 4 + r;
                float mm = fmaf(inv, a1[j][r], c1);
                float omx, ovx; adf_relu(mm, vv1, omx, ovx);
                oS[row * 408 + col] = f2bfbits(omx);
                vS[row * 408 + col] = f2bfbits(ovx);
            }
        }
    }
    __syncthreads();

    // ---- phase 1r: om/ov packets -> registers (c = tid + p*256 < 800) ----
    U4 oM[4], oV[4];
    #pragma unroll
    for (int p = 0; p < 4; ++p) {
        const int c = tid + p * 256;
        if (c < 800) {
            const int row = c / 50, k = (c - row * 50) * 8;
            oM[p].v = *(const bf16x8*)(oS + row * 408 + k);
            oV[p].v = *(const bf16x8*)(vS + row * 408 + k);
        }
    }
    __syncthreads();  // oS/vS reads done; pmS/pvS writes next (aliased)

    float sm[4] = {0, 0, 0, 0}, sm2[4] = {0, 0, 0, 0}, sv[4] = {0, 0, 0, 0};

    #pragma unroll 1
    for (int n = 0; n < 3; ++n) {
        // ---- products: (om*mask1, ov*mask1^2) -> pmS/pvS ----
        #pragma unroll
        for (int p = 0; p < 4; ++p) {
            const int c = tid + p * 256;
            if (c < 800) {
                const int row = c / 50, k = (c - row * 50) * 8;
                const size_t mb = ((size_t)n * B_N + m0 + row) * H1_N + k;
                float mf[8];
                if (bf) {
                    U4 mk; mk.u = *(const u32x4*)((const u16*)m1r + mb);
                    #pragma unroll
                    for (int j = 0; j < 8; ++j) mf[j] = bf2f(mk.s[j]);
                } else {
                    const f32x4* mp = (const f32x4*)m1r;
                    f32x4 q0 = mp[mb >> 2], q1 = mp[(mb >> 2) + 1];
                    #pragma unroll
                    for (int j = 0; j < 4; ++j) { mf[j] = q0[j]; mf[4 + j] = q1[j]; }
                }
                u16 pm[8], pv[8];
                #pragma unroll
                for (int j = 0; j < 8; ++j) {
                    pm[j] = f2bfbits(bf2f(oM[p].s[j]) * mf[j]);
                    pv[j] = f2bfbits(bf2f(oV[p].s[j]) * mf[j] * mf[j]);
                }
                *(u32x4*)(pmS + row * 408 + k) = *(u32x4*)pm;
                *(u32x4*)(pvS + row * 408 + k) = *(u32x4*)pv;
            }
        }
        __syncthreads();

        // ---- mask2 prefetch (independent of GEMM2) ----
        float m2p[5][4];
        #pragma unroll
        for (int j = 0; j < 5; ++j) {
            const int col = (cq + 4 * j) * 16 + lrow;
            #pragma unroll
            for (int r = 0; r < 4; ++r) {
                const int row = lgrp * 4 + r;
                float mv = 0.0f;
                if (col < H2_N) {
                    const size_t mi = ((size_t)n * B_N + m0 + row) * H2_N + col;
                    mv = bf ? bf2f(((const u16*)m2r)[mi]) : ((const float*)m2r)[mi];
                }
                m2p[j][r] = mv;
            }
        }

        // ---- layer2 GEMM (tiles t = cq + 4*j, j<5 -> cols 0..319) ----
        f32x4 accM[5], accV[5];
        #pragma unroll
        for (int j = 0; j < 5; ++j) { accM[j] = fz; accV[j] = fz; }
        #pragma unroll 1
        for (int ks = 0; ks < 12; ++ks) {
            const bf16x8 amf = *(const bf16x8*)(pmS + lrow * 408 + ks * 32 + lgrp * 8);
            const bf16x8 avf = *(const bf16x8*)(pvS + lrow * 408 + ks * 32 + lgrp * 8);
            const int kb = ks * 32 + lgrp * 8;
            #pragma unroll
            for (int j = 0; j < 5; ++j) {
                const int col = (cq + 4 * j) * 16 + lrow;
                U4 bm, bv; bm.u = 0; bv.u = 0;
                if (col < H2_N) {
                    const size_t bidx = (size_t)col * H1_N + kb;
                    bm.u = *(const u32x4*)(w2 + bidx);
                    bv.u = *(const u32x4*)(w2sqg + bidx);
                }
                accM[j] = MFMA16(amf, bm.v, accM[j]);
                accV[j] = MFMA16(avf, bv.v, accV[j]);
            }
        }
        {   // tail ks=12: k=384..400 valid -> zero lgrp>=2 A-fragments
            const bool kv = lgrp < 2;
            const int ko = kv ? lgrp * 8 : 0;
            U4 ta, tv;
            ta.v = *(const bf16x8*)(pmS + lrow * 408 + 384 + ko);
            tv.v = *(const bf16x8*)(pvS + lrow * 408 + 384 + ko);
            if (!kv) { ta.u = 0; tv.u = 0; }
            const int kb = 384 + lgrp * 8;
            #pragma unroll
            for (int j = 0; j < 5; ++j) {
                const int col = (cq + 4 * j) * 16 + lrow;
                U4 bm, bv; bm.u = 0; bv.u = 0;
                if (col < H2_N && kb < H1_N) {
                    const size_t bidx = (size_t)col * H1_N + kb;
                    bm.u = *(const u32x4*)(w2 + bidx);
                    bv.u = *(const u32x4*)(w2sqg + bidx);
                }
                accM[j] = MFMA16(ta.v, bm.v, accM[j]);
                accV[j] = MFMA16(tv.v, bv.v, accV[j]);
            }
        }
        __syncthreads();  // pmS/pvS reads done; m2s/v2s writes next (aliased)

        // ---- epilogue2: ADF ReLU + mask2 -> m2s/v2s ----
        #pragma unroll
        for (int j = 0; j < 5; ++j) {
            const int col = (cq + 4 * j) * 16 + lrow;
            const float b2v = (col < H2_N) ? b2f[col] : 0.0f;
            #pragma unroll
            for (int r = 0; r < 4; ++r) {
                const int rl = lgrp * 4 + r;
                u16 wm = 0, wvs = 0;
                if (col < H2_N) {
                    float omx, ovx;
                    adf_relu(accM[j][r] + b2v, accV[j][r], omx, ovx);
                    const float msk = m2p[j][r];
                    wm  = f2bfbits(omx * msk);
                    wvs = f2bfbits(ovx * msk * msk);
                }
                m2s[rl * 328 + col] = wm;
                v2s[rl * 328 + col] = wvs;
            }
        }
        __syncthreads();

        // ---- W3 GEMM: wv0 = mean slab, wv1 = var slab ----
        if (wv < 2) {
            const u16* slab = wv ? v2s : m2s;
            const u16* w3t  = wv ? w3vg : w3mg;
            f32x4 c3 = fz;
            #pragma unroll
            for (int kk = 0; kk < 10; ++kk) {
                bf16x8 af = *(const bf16x8*)(slab + lrow * 328 + kk * 32 + lgrp * 8);
                U4 bw; bw.u = *(const u32x4*)(w3t + (size_t)lrow * 320 + kk * 32 + lgrp * 8);
                c3 = MFMA16(af, bw.v, c3);
            }
            if (wv == 0) {
                #pragma unroll
                for (int r = 0; r < 4; ++r) { sm[r] += c3[r]; sm2[r] += c3[r] * c3[r]; }
            } else {
                #pragma unroll
                for (int r = 0; r < 4; ++r) sv[r] += c3[r];
            }
        }
        __syncthreads();  // m2s/v2s reuse by next n's products
    }

    // ---- final: wv1 -> exch -> wv0 writes outputs ----
    if (wv == 1 && lrow < A_N) {
        #pragma unroll
        for (int r = 0; r < 4; ++r) exch[(lgrp * 4 + r) * 8 + lrow] = sv[r];
    }
    __syncthreads();
    if (wv == 0 && lrow < A_N) {
        const float b3v = b3f[lrow];
        #pragma unroll
        for (int r = 0; r < 4; ++r) {
            const int rl = lgrp * 4 + r;
            const float svv = exch[rl * 8 + lrow];
            const float md = sm[r] * (1.0f / 3.0f);
            const float meanout = md + b3v;
            const float vexp = svv * (1.0f / 3.0f) + sm2[r] * (1.0f / 3.0f) - md * md;
            const float varout = __expf(vexp * 2.302585092994046f);  // 10^x
            const size_t rowg = (size_t)m0 + rl;
            if (bf) {
                ((u16*)outr)[rowg * 8 + lrow] = f2bfbits(meanout);
                ((u16*)outr)[(size_t)B_N * 8 + rowg * 8 + lrow] = f2bfbits(varout);
            } else {
                ((float*)outr)[rowg * 8 + lrow] = meanout;
                ((float*)outr)[(size_t)B_N * 8 + rowg * 8 + lrow] = varout;
            }
        }
    }
}

extern "C" void kernel_launch(void* const* d_in, const int* in_sizes, int n_in,
                              void* d_out, int out_size, void* d_ws, size_t ws_size,
                              hipStream_t stream) {
    const void* x     = d_in[0];
    // d_in[1] = x_noise (unused by reference)
    const void* W1    = d_in[2];
    const void* b1    = d_in[3];
    const void* W2    = d_in[4];
    const void* b2    = d_in[5];
    const void* W3    = d_in[6];
    const void* b3    = d_in[7];
    const void* mask1 = d_in[8];
    const void* mask2 = d_in[9];

    char* ws = (char*)d_ws;
    u32*   ctl   = (u32*)(ws + WS_CTL);
    float* b1f   = (float*)(ws + WS_B1F);
    float* b2f   = (float*)(ws + WS_B2F);
    float* b3f   = (float*)(ws + WS_B3F);
    float* rs1   = (float*)(ws + WS_RS1);
    float* vc1   = (float*)(ws + WS_VC1);
    u16*   w3m   = (u16*)(ws + WS_W3M);
    u16*   w3v   = (u16*)(ws + WS_W3V);
    u16*   w2sq  = (u16*)(ws + WS_W2SQ);
    u16*   w2b   = (u16*)(ws + WS_W2B);
    u16*   w1b   = (u16*)(ws + WS_W1B);

    k_detect<<<1, 64, 0, stream>>>((const u32*)x, ctl);
    k_weights<<<100, 256, 0, stream>>>(W1, W2, W3, b1, b2, b3, ctl,
                                       w1b, w2b, w2sq, w3m, w3v, b1f, b2f, b3f);
    k_minmax<<<2048, 256, 0, stream>>>(x, ctl);
    k_prep<<<400, 64, 0, stream>>>(W1, ctl, rs1, vc1);
    k_fused<<<2048, 256, 0, stream>>>(x, (const u16*)W1, w1b, (const u16*)W2, w2b,
                                      w2sq, mask1, mask2, b1f, b2f, b3f, rs1, vc1,
                                      w3m, w3v, ctl, d_out);
}